// Round 8
// baseline (397.057 us; speedup 1.0000x reference)
//
#include <hip/hip_runtime.h>
#include <math.h>

// ---- types ----
typedef __attribute__((ext_vector_type(8))) short short8;   // 8 bf16
typedef __attribute__((ext_vector_type(4))) short short4v;  // 4 bf16
typedef __attribute__((ext_vector_type(4))) float f32x4;

#define MFMA16(a, b, c) __builtin_amdgcn_mfma_f32_16x16x32_bf16(a, b, c, 0, 0, 0)

__device__ __forceinline__ short f2bf(float f) {
    union { float f; unsigned u; } v; v.f = f;
    unsigned r = v.u + 0x7fffu + ((v.u >> 16) & 1u);  // round-to-nearest-even
    return (short)(r >> 16);
}
__device__ __forceinline__ float bf2f(short s) {
    union { unsigned u; float f; } v; v.u = ((unsigned)(unsigned short)s) << 16;
    return v.f;
}
// tanh-form GELU: max abs err vs erf-GELU ~3e-3, well under the 0.18 threshold.
__device__ __forceinline__ float gelu(float v) {
    float u = v * (1.0f + 0.044715f * v * v);
    float e = exp2f(-2.3021184f * u);
    return v * __builtin_amdgcn_rcpf(1.0f + e);
}
__device__ __forceinline__ float max3f(float a, float b, float c) {
    float d; asm("v_max3_f32 %0, %1, %2, %3" : "=v"(d) : "v"(a), "v"(b), "v"(c)); return d;
}
// async global->LDS, 16B per lane; lds dest = wave-uniform base + lane*16 (m97/m104)
__device__ __forceinline__ void async16(const short* g, short* l) {
    __builtin_amdgcn_global_load_lds((const __attribute__((address_space(1))) void*)g,
                                     (__attribute__((address_space(3))) void*)l, 16, 0, 0);
}

// Redistribute 8 per-lane P values into the MFMA A-frag layout (see round-5 note).
__device__ __forceinline__ short8 build_pfrag(int lg, float x0, float x1, float x2, float x3,
                                              float x4, float x5, float x6, float x7) {
    unsigned a0, a1, b0, b1;
    asm("v_cvt_pk_bf16_f32 %0, %1, %2" : "=v"(a0) : "v"(x0), "v"(x1));
    asm("v_cvt_pk_bf16_f32 %0, %1, %2" : "=v"(a1) : "v"(x2), "v"(x3));
    asm("v_cvt_pk_bf16_f32 %0, %1, %2" : "=v"(b0) : "v"(x4), "v"(x5));
    asm("v_cvt_pk_bf16_f32 %0, %1, %2" : "=v"(b1) : "v"(x6), "v"(x7));
    unsigned u0 = (lg < 2) ? b0 : a0, u1 = (lg < 2) ? b1 : a1;
    unsigned v0 = (unsigned)__shfl_xor((int)u0, 32), v1 = (unsigned)__shfl_xor((int)u1, 32);
    unsigned w0 = (lg < 2) ? a0 : b0, w1 = (lg < 2) ? a1 : b1;
    bool sw = ((lg ^ (lg >> 1)) & 1) != 0;
    unsigned s0 = sw ? w0 : v0, s1 = sw ? w1 : v1;
    unsigned r0 = (unsigned)__shfl_xor((int)s0, 16), r1 = (unsigned)__shfl_xor((int)s1, 16);
    union { unsigned u[4]; short8 s; } o;
    o.u[0] = (lg & 1) ? r0 : ((lg == 0) ? w0 : v0);
    o.u[1] = (lg & 1) ? r1 : ((lg == 0) ? w1 : v1);
    o.u[2] = (lg & 1) ? ((lg == 1) ? v0 : w0) : r0;
    o.u[3] = (lg & 1) ? ((lg == 1) ? v1 : w1) : r1;
    return o.s;
}

// ---- cast x (f32 -> bf16), 4 elems/thread ----
__global__ __launch_bounds__(256) void cast_kernel(const float* __restrict__ in,
                                                   short* __restrict__ out, int n4) {
    int i = blockIdx.x * 256 + threadIdx.x;
    if (i < n4) {
        float4 v = ((const float4*)in)[i];
        short4v o;
        o.x = f2bf(v.x); o.y = f2bf(v.y); o.z = f2bf(v.z); o.w = f2bf(v.w);
        ((short4v*)out)[i] = o;
    }
}

// ---- concat q/k/v biases into one [2304] buffer ----
__global__ __launch_bounds__(256) void concat_bias(const float* __restrict__ a,
                                                   const float* __restrict__ b,
                                                   const float* __restrict__ c,
                                                   float* __restrict__ o) {
    int i = blockIdx.x * 256 + threadIdx.x;
    if (i < 768) o[i] = a[i];
    else if (i < 1536) o[i] = b[i - 768];
    else if (i < 2304) o[i] = c[i - 1536];
}

// ---- transpose+cast: in [K][N] f32  ->  out [N][K] bf16 ----
__global__ __launch_bounds__(256) void transpose_cast(const float* __restrict__ in,
                                                      short* __restrict__ out,
                                                      int K, int N) {
    __shared__ float tile[32][33];
    int n0 = blockIdx.x * 32, k0 = blockIdx.y * 32;
    int tx = threadIdx.x & 31, ty = threadIdx.x >> 5;  // 32 x 8
#pragma unroll
    for (int r = 0; r < 4; ++r)
        tile[ty + r * 8][tx] = in[(size_t)(k0 + ty + r * 8) * N + n0 + tx];
    __syncthreads();
#pragma unroll
    for (int r = 0; r < 4; ++r) {
        int rr = ty + r * 8;
        out[(size_t)(n0 + rr) * K + k0 + tx] = f2bf(tile[tx][rr]);
    }
}

// ---- per-head V transpose: in [96][1024 s][64 d] bf16 -> out [96][64 d][1024 s] ----
__global__ __launch_bounds__(256) void transpose_v(const short* __restrict__ in,
                                                   short* __restrict__ out) {
    __shared__ short tile[32][33];
    const int bh = blockIdx.z;
    const int s0 = blockIdx.y * 32, d0 = blockIdx.x * 32;
    const short* src = in + (size_t)bh * 1024 * 64;
    short* dst = out + (size_t)bh * 64 * 1024;
    int tx = threadIdx.x & 31, ty = threadIdx.x >> 5;  // 32 x 8
#pragma unroll
    for (int r = 0; r < 4; ++r)
        tile[ty + r * 8][tx] = src[(size_t)(s0 + ty + r * 8) * 64 + d0 + tx];
    __syncthreads();
#pragma unroll
    for (int r = 0; r < 4; ++r) {
        int rr = ty + r * 8;
        dst[(size_t)(d0 + rr) * 1024 + s0 + tx] = tile[tx][rr];
    }
}

// ---- generic bf16 GEMM: C[M,N] = A[M,K] @ B[K,N] (+bias, epilogue) ----
// BK=64, XOR-swizzled LDS (both-sides). See round-6/7 notes. b128 reads at the
// 8-lane/window floor (optimal for b128).
// EPI 0: QKV scatter; q (m==0) pre-scaled by 0.125*log2e for exp2-domain attn.
template <int EPI, int NF>
__global__ __launch_bounds__(256) void gemm_kernel(const short* __restrict__ A,
                                                   const short* __restrict__ Bt,
                                                   const float* __restrict__ bias,
                                                   void* __restrict__ Cout,
                                                   const float* __restrict__ resid,
                                                   int M, int N, int K) {
    const int TN = NF * 32;
    const int t = threadIdx.x;
    const int wid = t >> 6, lane = t & 63;
    const int wm = wid >> 1, wn = wid & 1;
    const int lr = lane & 15, lg = lane >> 4;
    const int row0 = blockIdx.y * 128, col0 = blockIdx.x * TN;

    __shared__ __align__(16) short As[128 * 64];
    __shared__ __align__(16) short Bs[NF * 32 * 64];

    f32x4 acc[4][NF];
#pragma unroll
    for (int i = 0; i < 4; ++i)
#pragma unroll
        for (int j = 0; j < NF; ++j) acc[i][j] = (f32x4){0.f, 0.f, 0.f, 0.f};

    const int aRow = wid * 8 + (lane >> 3);
    const int aK = ((lane & 7) ^ (lane >> 3)) << 3;
    const short* Ag = A + (size_t)(row0 + aRow) * K + aK;
    const short* Bg = Bt + (size_t)(col0 + aRow) * K + aK;
    short* AsW = As + wid * 8 * 64;
    short* BsW = Bs + wid * 8 * 64;
    const int swz = lr & 7;

    for (int k0 = 0; k0 < K; k0 += 64) {
        __syncthreads();
#pragma unroll
        for (int j = 0; j < 4; ++j)
            async16(Ag + (size_t)(j * 32) * K + k0, AsW + j * 32 * 64);
#pragma unroll
        for (int j = 0; j < NF; ++j)
            async16(Bg + (size_t)(j * 32) * K + k0, BsW + j * 32 * 64);
        __syncthreads();

#pragma unroll
        for (int ks = 0; ks < 2; ++ks) {
            const int rdofs = ((ks * 4 + lg) ^ swz) << 3;
            short8 af[4], bfr[NF];
#pragma unroll
            for (int i = 0; i < 4; ++i)
                af[i] = *(short8*)(As + (wm * 64 + i * 16 + lr) * 64 + rdofs);
#pragma unroll
            for (int i = 0; i < NF; ++i)
                bfr[i] = *(short8*)(Bs + (wn * (NF * 16) + i * 16 + lr) * 64 + rdofs);
#pragma unroll
            for (int mi = 0; mi < 4; ++mi)
#pragma unroll
                for (int ni = 0; ni < NF; ++ni)
                    acc[mi][ni] = MFMA16(af[mi], bfr[ni], acc[mi][ni]);
        }
    }

#pragma unroll
    for (int mi = 0; mi < 4; ++mi)
#pragma unroll
        for (int ni = 0; ni < NF; ++ni)
#pragma unroll
            for (int r = 0; r < 4; ++r) {
                int row = row0 + wm * 64 + mi * 16 + lg * 4 + r;
                int col = col0 + wn * (NF * 16) + ni * 16 + lr;
                float v = acc[mi][ni][r] + bias[col];
                if constexpr (EPI == 0) {
                    unsigned uc = (unsigned)col;
                    unsigned m = uc / 768u;
                    unsigned rest = uc - m * 768u;
                    unsigned h = rest >> 6, d = rest & 63u;
                    int b = row >> 10, s_ = row & 1023;
                    if (m == 0u) v *= 0.18033688011f;  // fold 1/sqrt(64)*log2e into Q
                    ((short*)Cout)[((((size_t)m * 96 + (size_t)b * 12 + h) * 1024 + s_) * 64) + d] = f2bf(v);
                } else if constexpr (EPI == 1) {
                    ((short*)Cout)[(size_t)row * N + col] = f2bf(gelu(v));
                } else {
                    size_t idx = (size_t)row * N + col;
                    ((float*)Cout)[idx] = resid[idx] + gelu(v);
                }
            }
}

// ---- flash attention: swapped QK^T, in-register softmax, defer-max,
//      async16+XOR-swizzled Q/K/V staging (linear [64][64] LDS) ----
// Q pre-scaled by 0.125*log2e at projection (scores in exp2 domain).
__global__ __launch_bounds__(256) void attn_kernel(const short* __restrict__ Q,
                                                   const short* __restrict__ Kg,
                                                   const short* __restrict__ VTg,
                                                   short* __restrict__ ctx) {
    const int bh = blockIdx.x;       // 0..95
    const int q0 = blockIdx.y * 64;  // 16 q-blocks
    const int t = threadIdx.x, wid = t >> 6, lane = t & 63;
    const int lr = lane & 15, lg = lane >> 4;

    __shared__ __align__(16) short Qs[64 * 64];
    __shared__ __align__(16) short Ks[64 * 64];
    __shared__ __align__(16) short Vt[64 * 64];  // [d][k]

    const size_t base = (size_t)bh * 1024 * 64;
    const size_t vbase = (size_t)bh * 64 * 1024;

    // staging decomposition: lane -> (srow = lane/8, phys slot = lane&7);
    // source k/d-slot pre-swizzled: lslot = (lane&7)^srow (rule #21 both-sides)
    const int srow = lane >> 3;
    const int lslot8 = ((lane & 7) ^ srow) << 3;
    const int r0w = wid * 16;
    const int swz = lr & 7;

    // ---- Q stage (once) ----
    {
        const short* g = Q + base + (size_t)(q0 + r0w + srow) * 64 + lslot8;
        async16(g, Qs + r0w * 64);
        async16(g + 8 * 64, Qs + (r0w + 8) * 64);
    }
    __syncthreads();
    short8 qf[2];
    qf[0] = *(short8*)(Qs + (r0w + lr) * 64 + ((lg ^ swz) << 3));
    qf[1] = *(short8*)(Qs + (r0w + lr) * 64 + (((4 + lg) ^ swz) << 3));

    f32x4 oacc[4];
#pragma unroll
    for (int i = 0; i < 4; ++i) oacc[i] = (f32x4){0.f, 0.f, 0.f, 0.f};
    float mrun = -1e30f, lrun = 0.f;  // per-lane, for q = q0 + r0w + lr

    const short* kg = Kg + base + (size_t)(r0w + srow) * 64 + lslot8;
    const short* vg = VTg + vbase + (size_t)(r0w + srow) * 1024 + lslot8;

    for (int kt = 0; kt < 16; ++kt) {
        const int krow0 = kt * 64;
        __syncthreads();
        async16(kg + (size_t)krow0 * 64, Ks + r0w * 64);
        async16(kg + (size_t)(krow0 + 8) * 64, Ks + (r0w + 8) * 64);
        async16(vg + krow0, Vt + r0w * 64);
        async16(vg + krow0 + 8 * 1024, Vt + (r0w + 8) * 64);
        __syncthreads();

        // S^T = mfma(K, Q): lane holds 16 exp2-domain scores for q-row lr
        f32x4 sfr[4];
#pragma unroll
        for (int cf = 0; cf < 4; ++cf) {
            f32x4 s = (f32x4){0.f, 0.f, 0.f, 0.f};
            short8 kf0 = *(short8*)(Ks + (cf * 16 + lr) * 64 + ((lg ^ swz) << 3));
            short8 kf1 = *(short8*)(Ks + (cf * 16 + lr) * 64 + (((4 + lg) ^ swz) << 3));
            s = MFMA16(kf0, qf[0], s);
            s = MFMA16(kf1, qf[1], s);
            sfr[cf] = s;
        }

        // row max via max3 tree + 2 shfl
        float g0 = max3f(sfr[0][0], sfr[0][1], sfr[0][2]);
        float g1 = max3f(sfr[0][3], sfr[1][0], sfr[1][1]);
        float g2 = max3f(sfr[1][2], sfr[1][3], sfr[2][0]);
        float g3 = max3f(sfr[2][1], sfr[2][2], sfr[2][3]);
        float g4 = max3f(sfr[3][0], sfr[3][1], sfr[3][2]);
        float mx = fmaxf(max3f(g0, g1, g2), max3f(g3, g4, sfr[3][3]));
        mx = fmaxf(mx, __shfl_xor(mx, 16));
        mx = fmaxf(mx, __shfl_xor(mx, 32));

        // defer-max (T13): only rescale when max grew past THR=8 (P <= 2^8)
        if (!__all(mx <= mrun + 8.0f)) {
            float mnew = fmaxf(mrun, mx);
            float fac = exp2f(mrun - mnew);
            lrun *= fac;
#pragma unroll
            for (int r = 0; r < 4; ++r) {
                float fr = __shfl(fac, lg * 4 + r);
#pragma unroll
                for (int df = 0; df < 4; ++df) oacc[df][r] *= fr;
            }
            mrun = mnew;
        }

        float p[16];
#pragma unroll
        for (int cf = 0; cf < 4; ++cf)
#pragma unroll
            for (int r = 0; r < 4; ++r) p[cf * 4 + r] = exp2f(sfr[cf][r] - mrun);
        float s0 = (p[0] + p[1]) + (p[2] + p[3]);
        float s1 = (p[4] + p[5]) + (p[6] + p[7]);
        float s2 = (p[8] + p[9]) + (p[10] + p[11]);
        float s3 = (p[12] + p[13]) + (p[14] + p[15]);
        float rs = (s0 + s1) + (s2 + s3);
        rs += __shfl_xor(rs, 16);
        rs += __shfl_xor(rs, 32);
        lrun += rs;

        short8 pf0 = build_pfrag(lg, p[0], p[1], p[2], p[3], p[4], p[5], p[6], p[7]);
        short8 pf1 = build_pfrag(lg, p[8], p[9], p[10], p[11], p[12], p[13], p[14], p[15]);
#pragma unroll
        for (int df = 0; df < 4; ++df) {
            short8 vf0 = *(short8*)(Vt + (df * 16 + lr) * 64 + ((lg ^ swz) << 3));
            oacc[df] = MFMA16(pf0, vf0, oacc[df]);
        }
#pragma unroll
        for (int df = 0; df < 4; ++df) {
            short8 vf1 = *(short8*)(Vt + (df * 16 + lr) * 64 + (((4 + lg) ^ swz) << 3));
            oacc[df] = MFMA16(pf1, vf1, oacc[df]);
        }
    }

    const int b = bh / 12, h = bh % 12;
    float rinv[4];
#pragma unroll
    for (int r = 0; r < 4; ++r) {
        float lr_ = __shfl(lrun, lg * 4 + r);
        rinv[r] = __builtin_amdgcn_rcpf(lr_);
    }
#pragma unroll
    for (int df = 0; df < 4; ++df)
#pragma unroll
        for (int r = 0; r < 4; ++r) {
            int q = q0 + wid * 16 + lg * 4 + r;
            int d = df * 16 + lr;
            float o = oacc[df][r] * rinv[r];
            ctx[((size_t)b * 1024 + q) * 768 + h * 64 + d] = f2bf(o);
        }
}

// ---- fused: x2 = x + LN1(ctx);  ln2b = bf16(LN2(x2)) ----
__global__ __launch_bounds__(256) void ln_fused(const float* __restrict__ x,
                                                const short* __restrict__ ctx,
                                                const float* __restrict__ g1,
                                                const float* __restrict__ b1,
                                                const float* __restrict__ g2,
                                                const float* __restrict__ b2,
                                                float* __restrict__ x2,
                                                short* __restrict__ ln2b) {
    const int row = blockIdx.x, t = threadIdx.x;
    const int wid = t >> 6, lane = t & 63;
    __shared__ float red[8];

    float c[3], xv[3];
#pragma unroll
    for (int j = 0; j < 3; ++j) {
        int idx = t + 256 * j;
        c[j] = bf2f(ctx[(size_t)row * 768 + idx]);
        xv[j] = x[(size_t)row * 768 + idx];
    }
    float s = c[0] + c[1] + c[2];
    float s2 = c[0] * c[0] + c[1] * c[1] + c[2] * c[2];
#pragma unroll
    for (int off = 32; off > 0; off >>= 1) { s += __shfl_down(s, off); s2 += __shfl_down(s2, off); }
    if (lane == 0) { red[wid] = s; red[4 + wid] = s2; }
    __syncthreads();
    s = red[0] + red[1] + red[2] + red[3];
    s2 = red[4] + red[5] + red[6] + red[7];
    float mu = s * (1.0f / 768.0f);
    float rstd = rsqrtf(s2 * (1.0f / 768.0f) - mu * mu + 1e-5f);

    float y[3];
#pragma unroll
    for (int j = 0; j < 3; ++j) {
        int idx = t + 256 * j;
        y[j] = xv[j] + (c[j] - mu) * rstd * g1[idx] + b1[idx];
        x2[(size_t)row * 768 + idx] = y[j];
    }
    __syncthreads();
    s = y[0] + y[1] + y[2];
    s2 = y[0] * y[0] + y[1] * y[1] + y[2] * y[2];
#pragma unroll
    for (int off = 32; off > 0; off >>= 1) { s += __shfl_down(s, off); s2 += __shfl_down(s2, off); }
    if (lane == 0) { red[wid] = s; red[4 + wid] = s2; }
    __syncthreads();
    s = red[0] + red[1] + red[2] + red[3];
    s2 = red[4] + red[5] + red[6] + red[7];
    float mu2 = s * (1.0f / 768.0f);
    float rstd2 = rsqrtf(s2 * (1.0f / 768.0f) - mu2 * mu2 + 1e-5f);
#pragma unroll
    for (int j = 0; j < 3; ++j) {
        int idx = t + 256 * j;
        ln2b[(size_t)row * 768 + idx] = f2bf((y[j] - mu2) * rstd2 * g2[idx] + b2[idx]);
    }
}

extern "C" void kernel_launch(void* const* d_in, const int* in_sizes, int n_in,
                              void* d_out, int out_size, void* d_ws, size_t ws_size,
                              hipStream_t stream) {
    const float* x    = (const float*)d_in[0];
    const float* wq   = (const float*)d_in[1];
    const float* bq   = (const float*)d_in[2];
    const float* wk   = (const float*)d_in[3];
    const float* bk   = (const float*)d_in[4];
    const float* wv   = (const float*)d_in[5];
    const float* bv   = (const float*)d_in[6];
    const float* g1   = (const float*)d_in[7];
    const float* b1   = (const float*)d_in[8];
    const float* g2   = (const float*)d_in[9];
    const float* b2   = (const float*)d_in[10];
    const float* w_in = (const float*)d_in[11];
    const float* b_in = (const float*)d_in[12];
    const float* w_out  = (const float*)d_in[13];
    const float* b_out  = (const float*)d_in[14];
    float* out = (float*)d_out;

    char* ws = (char*)d_ws;
    short* xb     = (short*)(ws + 0);          // 12.6 MB; dead after QKV gemm
    short* vT     = (short*)(ws + 0);          // aliases xb
    short* qb     = (short*)(ws + 12582912);   // [96][1024][64] q,k,v contiguous
    short* kb     = (short*)(ws + 25165824);
    short* vb     = (short*)(ws + 37748736);
    short* h1     = (short*)(ws + 0);          // 50.3 MB, aliases xb/vT..vb
    short* ctx    = (short*)(ws + 50331648);   // 12.6 MB
    float* x2     = (float*)(ws + 62914560);   // 25.2 MB
    float* bqkv   = (float*)(ws + 62914560);   // aliases x2 start
    short* ln2b   = (short*)(ws + 88080384);   // 12.6 MB
    short* wqkvT  = (short*)(ws + 100663296);  // [2304][768]
    short* w_inT  = (short*)(ws + 104202240);  // [3072][768]
    short* w_outT = (short*)(ws + 108920832);  // [768][3072]

    // stage 0
    cast_kernel<<<6144, 256, 0, stream>>>(x, xb, 1572864);
    concat_bias<<<9, 256, 0, stream>>>(bq, bk, bv, bqkv);
    transpose_cast<<<dim3(24, 24), 256, 0, stream>>>(wq, wqkvT, 768, 768);
    transpose_cast<<<dim3(24, 24), 256, 0, stream>>>(wk, wqkvT + 768 * 768, 768, 768);
    transpose_cast<<<dim3(24, 24), 256, 0, stream>>>(wv, wqkvT + 2 * 768 * 768, 768, 768);
    transpose_cast<<<dim3(96, 24), 256, 0, stream>>>(w_in, w_inT, 768, 3072);
    transpose_cast<<<dim3(24, 96), 256, 0, stream>>>(w_out, w_outT, 3072, 768);

    // stage 1: fused QKV projection (q pre-scaled in epilogue)
    gemm_kernel<0, 4><<<dim3(18, 64), 256, 0, stream>>>(xb, wqkvT, bqkv, qb, nullptr, 8192, 2304, 768);

    // stage 1.5: V transpose
    transpose_v<<<dim3(2, 32, 96), 256, 0, stream>>>(vb, vT);

    // stage 2: attention
    attn_kernel<<<dim3(96, 16), 256, 0, stream>>>(qb, kb, vT, ctx);

    // stage 3
    ln_fused<<<8192, 256, 0, stream>>>(x, ctx, g1, b1, g2, b2, x2, ln2b);

    // stage 4: MLP
    gemm_kernel<1, 4><<<dim3(24, 64), 256, 0, stream>>>(ln2b, w_inT, b_in, h1, nullptr, 8192, 3072, 768);
    gemm_kernel<2, 4><<<dim3(6, 64), 256, 0, stream>>>(h1, w_outT, b_out, out, x2, 8192, 768, 3072);
}

// Round 9
// 372.295 us; speedup vs baseline: 1.0665x; 1.0665x over previous
//
#include <hip/hip_runtime.h>
#include <math.h>

// ---- types ----
typedef __attribute__((ext_vector_type(8))) short short8;   // 8 bf16
typedef __attribute__((ext_vector_type(4))) short short4v;  // 4 bf16
typedef __attribute__((ext_vector_type(4))) float f32x4;

#define MFMA16(a, b, c) __builtin_amdgcn_mfma_f32_16x16x32_bf16(a, b, c, 0, 0, 0)

__device__ __forceinline__ short f2bf(float f) {
    union { float f; unsigned u; } v; v.f = f;
    unsigned r = v.u + 0x7fffu + ((v.u >> 16) & 1u);  // round-to-nearest-even
    return (short)(r >> 16);
}
__device__ __forceinline__ float bf2f(short s) {
    union { unsigned u; float f; } v; v.u = ((unsigned)(unsigned short)s) << 16;
    return v.f;
}
// tanh-form GELU: max abs err vs erf-GELU ~3e-3, well under the 0.18 threshold.
__device__ __forceinline__ float gelu(float v) {
    float u = v * (1.0f + 0.044715f * v * v);
    float e = exp2f(-2.3021184f * u);
    return v * __builtin_amdgcn_rcpf(1.0f + e);
}
__device__ __forceinline__ float max3f(float a, float b, float c) {
    float d; asm("v_max3_f32 %0, %1, %2, %3" : "=v"(d) : "v"(a), "v"(b), "v"(c)); return d;
}
// async global->LDS, 16B per lane; lds dest = wave-uniform base + lane*16 (m97/m104)
__device__ __forceinline__ void async16(const short* g, short* l) {
    __builtin_amdgcn_global_load_lds((const __attribute__((address_space(1))) void*)g,
                                     (__attribute__((address_space(3))) void*)l, 16, 0, 0);
}

// Redistribute 8 per-lane P values into the MFMA A-frag layout (see round-5 note).
__device__ __forceinline__ short8 build_pfrag(int lg, float x0, float x1, float x2, float x3,
                                              float x4, float x5, float x6, float x7) {
    unsigned a0, a1, b0, b1;
    asm("v_cvt_pk_bf16_f32 %0, %1, %2" : "=v"(a0) : "v"(x0), "v"(x1));
    asm("v_cvt_pk_bf16_f32 %0, %1, %2" : "=v"(a1) : "v"(x2), "v"(x3));
    asm("v_cvt_pk_bf16_f32 %0, %1, %2" : "=v"(b0) : "v"(x4), "v"(x5));
    asm("v_cvt_pk_bf16_f32 %0, %1, %2" : "=v"(b1) : "v"(x6), "v"(x7));
    unsigned u0 = (lg < 2) ? b0 : a0, u1 = (lg < 2) ? b1 : a1;
    unsigned v0 = (unsigned)__shfl_xor((int)u0, 32), v1 = (unsigned)__shfl_xor((int)u1, 32);
    unsigned w0 = (lg < 2) ? a0 : b0, w1 = (lg < 2) ? a1 : b1;
    bool sw = ((lg ^ (lg >> 1)) & 1) != 0;
    unsigned s0 = sw ? w0 : v0, s1 = sw ? w1 : v1;
    unsigned r0 = (unsigned)__shfl_xor((int)s0, 16), r1 = (unsigned)__shfl_xor((int)s1, 16);
    union { unsigned u[4]; short8 s; } o;
    o.u[0] = (lg & 1) ? r0 : ((lg == 0) ? w0 : v0);
    o.u[1] = (lg & 1) ? r1 : ((lg == 0) ? w1 : v1);
    o.u[2] = (lg & 1) ? ((lg == 1) ? v0 : w0) : r0;
    o.u[3] = (lg & 1) ? ((lg == 1) ? v1 : w1) : r1;
    return o.s;
}

// ---- cast x (f32 -> bf16), 4 elems/thread ----
__global__ __launch_bounds__(256) void cast_kernel(const float* __restrict__ in,
                                                   short* __restrict__ out, int n4) {
    int i = blockIdx.x * 256 + threadIdx.x;
    if (i < n4) {
        float4 v = ((const float4*)in)[i];
        short4v o;
        o.x = f2bf(v.x); o.y = f2bf(v.y); o.z = f2bf(v.z); o.w = f2bf(v.w);
        ((short4v*)out)[i] = o;
    }
}

// ---- concat q/k/v biases into one [2304] buffer ----
__global__ __launch_bounds__(256) void concat_bias(const float* __restrict__ a,
                                                   const float* __restrict__ b,
                                                   const float* __restrict__ c,
                                                   float* __restrict__ o) {
    int i = blockIdx.x * 256 + threadIdx.x;
    if (i < 768) o[i] = a[i];
    else if (i < 1536) o[i] = b[i - 768];
    else if (i < 2304) o[i] = c[i - 1536];
}

// ---- transpose+cast: in [K][N] f32  ->  out [N][K] bf16 ----
__global__ __launch_bounds__(256) void transpose_cast(const float* __restrict__ in,
                                                      short* __restrict__ out,
                                                      int K, int N) {
    __shared__ float tile[32][33];
    int n0 = blockIdx.x * 32, k0 = blockIdx.y * 32;
    int tx = threadIdx.x & 31, ty = threadIdx.x >> 5;  // 32 x 8
#pragma unroll
    for (int r = 0; r < 4; ++r)
        tile[ty + r * 8][tx] = in[(size_t)(k0 + ty + r * 8) * N + n0 + tx];
    __syncthreads();
#pragma unroll
    for (int r = 0; r < 4; ++r) {
        int rr = ty + r * 8;
        out[(size_t)(n0 + rr) * K + k0 + tx] = f2bf(tile[tx][rr]);
    }
}

// ---- per-head V transpose: in [96][1024 s][64 d] bf16 -> out [96][64 d][1024 s] ----
__global__ __launch_bounds__(256) void transpose_v(const short* __restrict__ in,
                                                   short* __restrict__ out) {
    __shared__ short tile[32][33];
    const int bh = blockIdx.z;
    const int s0 = blockIdx.y * 32, d0 = blockIdx.x * 32;
    const short* src = in + (size_t)bh * 1024 * 64;
    short* dst = out + (size_t)bh * 64 * 1024;
    int tx = threadIdx.x & 31, ty = threadIdx.x >> 5;  // 32 x 8
#pragma unroll
    for (int r = 0; r < 4; ++r)
        tile[ty + r * 8][tx] = src[(size_t)(s0 + ty + r * 8) * 64 + d0 + tx];
    __syncthreads();
#pragma unroll
    for (int r = 0; r < 4; ++r) {
        int rr = ty + r * 8;
        dst[(size_t)(d0 + rr) * 1024 + s0 + tx] = tile[tx][rr];
    }
}

// ---- generic bf16 GEMM: C[M,N] = A[M,K] @ B[K,N] (+bias, epilogue) ----
// BK=64, XOR-swizzled LDS (both-sides), MB-row x NF*32-col tile, 4 waves (2x2).
// 1-D grid with bijective XCD swizzle (T1): xcd = wgid&7 owns a contiguous chunk
// of row-blocks WITH all NXB col-blocks -> A-panel sharers hit the same L2.
// rb = xcd*rpx + loc/NXB, cb = loc%NXB  (rpx = (M/MB)/8; requires (M/MB)%8==0).
template <int EPI, int NF, int MB, int NXB>
__global__ __launch_bounds__(256) void gemm_kernel(const short* __restrict__ A,
                                                   const short* __restrict__ Bt,
                                                   const float* __restrict__ bias,
                                                   void* __restrict__ Cout,
                                                   const float* __restrict__ resid,
                                                   int M, int N, int K) {
    const int TN = NF * 32;
    const int FM = MB / 32;  // A-frags per wave
    const int t = threadIdx.x;
    const int wid = t >> 6, lane = t & 63;
    const int wm = wid >> 1, wn = wid & 1;
    const int lr = lane & 15, lg = lane >> 4;

    const int wgid = blockIdx.x;
    const int xcd = wgid & 7;
    const int loc = wgid >> 3;
    const int rpx = (M / MB) >> 3;  // row-blocks per XCD
    const int rb = xcd * rpx + loc / NXB;
    const int cb = loc % NXB;
    const int row0 = rb * MB, col0 = cb * TN;

    __shared__ __align__(16) short As[MB * 64];
    __shared__ __align__(16) short Bs[NF * 32 * 64];

    f32x4 acc[FM][NF];
#pragma unroll
    for (int i = 0; i < FM; ++i)
#pragma unroll
        for (int j = 0; j < NF; ++j) acc[i][j] = (f32x4){0.f, 0.f, 0.f, 0.f};

    const int aRow = wid * 8 + (lane >> 3);
    const int aK = ((lane & 7) ^ (lane >> 3)) << 3;
    const short* Ag = A + (size_t)(row0 + aRow) * K + aK;
    const short* Bg = Bt + (size_t)(col0 + aRow) * K + aK;
    short* AsW = As + wid * 8 * 64;
    short* BsW = Bs + wid * 8 * 64;
    const int swz = lr & 7;

    for (int k0 = 0; k0 < K; k0 += 64) {
        __syncthreads();
#pragma unroll
        for (int j = 0; j < MB / 32; ++j)
            async16(Ag + (size_t)(j * 32) * K + k0, AsW + j * 32 * 64);
#pragma unroll
        for (int j = 0; j < NF; ++j)
            async16(Bg + (size_t)(j * 32) * K + k0, BsW + j * 32 * 64);
        __syncthreads();

#pragma unroll
        for (int ks = 0; ks < 2; ++ks) {
            const int rdofs = ((ks * 4 + lg) ^ swz) << 3;
            short8 af[FM], bfr[NF];
#pragma unroll
            for (int i = 0; i < FM; ++i)
                af[i] = *(short8*)(As + (wm * (MB / 2) + i * 16 + lr) * 64 + rdofs);
#pragma unroll
            for (int i = 0; i < NF; ++i)
                bfr[i] = *(short8*)(Bs + (wn * (NF * 16) + i * 16 + lr) * 64 + rdofs);
#pragma unroll
            for (int mi = 0; mi < FM; ++mi)
#pragma unroll
                for (int ni = 0; ni < NF; ++ni)
                    acc[mi][ni] = MFMA16(af[mi], bfr[ni], acc[mi][ni]);
        }
    }

#pragma unroll
    for (int mi = 0; mi < FM; ++mi)
#pragma unroll
        for (int ni = 0; ni < NF; ++ni)
#pragma unroll
            for (int r = 0; r < 4; ++r) {
                int row = row0 + wm * (MB / 2) + mi * 16 + lg * 4 + r;
                int col = col0 + wn * (NF * 16) + ni * 16 + lr;
                float v = acc[mi][ni][r] + bias[col];
                if constexpr (EPI == 0) {
                    unsigned uc = (unsigned)col;
                    unsigned m = uc / 768u;
                    unsigned rest = uc - m * 768u;
                    unsigned h = rest >> 6, d = rest & 63u;
                    int b = row >> 10, s_ = row & 1023;
                    if (m == 0u) v *= 0.18033688011f;  // fold 1/sqrt(64)*log2e into Q
                    ((short*)Cout)[((((size_t)m * 96 + (size_t)b * 12 + h) * 1024 + s_) * 64) + d] = f2bf(v);
                } else if constexpr (EPI == 1) {
                    ((short*)Cout)[(size_t)row * N + col] = f2bf(gelu(v));
                } else {
                    size_t idx = (size_t)row * N + col;
                    ((float*)Cout)[idx] = resid[idx] + gelu(v);
                }
            }
}

// ---- flash attention: swapped QK^T, in-register softmax, defer-max,
//      async16+XOR-swizzled Q/K/V staging (unchanged from round 7) ----
__global__ __launch_bounds__(256) void attn_kernel(const short* __restrict__ Q,
                                                   const short* __restrict__ Kg,
                                                   const short* __restrict__ VTg,
                                                   short* __restrict__ ctx) {
    const int bh = blockIdx.x;       // 0..95
    const int q0 = blockIdx.y * 64;  // 16 q-blocks
    const int t = threadIdx.x, wid = t >> 6, lane = t & 63;
    const int lr = lane & 15, lg = lane >> 4;

    __shared__ __align__(16) short Qs[64 * 64];
    __shared__ __align__(16) short Ks[64 * 64];
    __shared__ __align__(16) short Vt[64 * 64];  // [d][k]

    const size_t base = (size_t)bh * 1024 * 64;
    const size_t vbase = (size_t)bh * 64 * 1024;

    const int srow = lane >> 3;
    const int lslot8 = ((lane & 7) ^ srow) << 3;
    const int r0w = wid * 16;
    const int swz = lr & 7;

    {
        const short* g = Q + base + (size_t)(q0 + r0w + srow) * 64 + lslot8;
        async16(g, Qs + r0w * 64);
        async16(g + 8 * 64, Qs + (r0w + 8) * 64);
    }
    __syncthreads();
    short8 qf[2];
    qf[0] = *(short8*)(Qs + (r0w + lr) * 64 + ((lg ^ swz) << 3));
    qf[1] = *(short8*)(Qs + (r0w + lr) * 64 + (((4 + lg) ^ swz) << 3));

    f32x4 oacc[4];
#pragma unroll
    for (int i = 0; i < 4; ++i) oacc[i] = (f32x4){0.f, 0.f, 0.f, 0.f};
    float mrun = -1e30f, lrun = 0.f;

    const short* kg = Kg + base + (size_t)(r0w + srow) * 64 + lslot8;
    const short* vg = VTg + vbase + (size_t)(r0w + srow) * 1024 + lslot8;

    for (int kt = 0; kt < 16; ++kt) {
        const int krow0 = kt * 64;
        __syncthreads();
        async16(kg + (size_t)krow0 * 64, Ks + r0w * 64);
        async16(kg + (size_t)(krow0 + 8) * 64, Ks + (r0w + 8) * 64);
        async16(vg + krow0, Vt + r0w * 64);
        async16(vg + krow0 + 8 * 1024, Vt + (r0w + 8) * 64);
        __syncthreads();

        f32x4 sfr[4];
#pragma unroll
        for (int cf = 0; cf < 4; ++cf) {
            f32x4 s = (f32x4){0.f, 0.f, 0.f, 0.f};
            short8 kf0 = *(short8*)(Ks + (cf * 16 + lr) * 64 + ((lg ^ swz) << 3));
            short8 kf1 = *(short8*)(Ks + (cf * 16 + lr) * 64 + (((4 + lg) ^ swz) << 3));
            s = MFMA16(kf0, qf[0], s);
            s = MFMA16(kf1, qf[1], s);
            sfr[cf] = s;
        }

        float g0 = max3f(sfr[0][0], sfr[0][1], sfr[0][2]);
        float g1 = max3f(sfr[0][3], sfr[1][0], sfr[1][1]);
        float g2 = max3f(sfr[1][2], sfr[1][3], sfr[2][0]);
        float g3 = max3f(sfr[2][1], sfr[2][2], sfr[2][3]);
        float g4 = max3f(sfr[3][0], sfr[3][1], sfr[3][2]);
        float mx = fmaxf(max3f(g0, g1, g2), max3f(g3, g4, sfr[3][3]));
        mx = fmaxf(mx, __shfl_xor(mx, 16));
        mx = fmaxf(mx, __shfl_xor(mx, 32));

        if (!__all(mx <= mrun + 8.0f)) {
            float mnew = fmaxf(mrun, mx);
            float fac = exp2f(mrun - mnew);
            lrun *= fac;
#pragma unroll
            for (int r = 0; r < 4; ++r) {
                float fr = __shfl(fac, lg * 4 + r);
#pragma unroll
                for (int df = 0; df < 4; ++df) oacc[df][r] *= fr;
            }
            mrun = mnew;
        }

        float p[16];
#pragma unroll
        for (int cf = 0; cf < 4; ++cf)
#pragma unroll
            for (int r = 0; r < 4; ++r) p[cf * 4 + r] = exp2f(sfr[cf][r] - mrun);
        float s0 = (p[0] + p[1]) + (p[2] + p[3]);
        float s1 = (p[4] + p[5]) + (p[6] + p[7]);
        float s2 = (p[8] + p[9]) + (p[10] + p[11]);
        float s3 = (p[12] + p[13]) + (p[14] + p[15]);
        float rs = (s0 + s1) + (s2 + s3);
        rs += __shfl_xor(rs, 16);
        rs += __shfl_xor(rs, 32);
        lrun += rs;

        short8 pf0 = build_pfrag(lg, p[0], p[1], p[2], p[3], p[4], p[5], p[6], p[7]);
        short8 pf1 = build_pfrag(lg, p[8], p[9], p[10], p[11], p[12], p[13], p[14], p[15]);
#pragma unroll
        for (int df = 0; df < 4; ++df) {
            short8 vf0 = *(short8*)(Vt + (df * 16 + lr) * 64 + ((lg ^ swz) << 3));
            oacc[df] = MFMA16(pf0, vf0, oacc[df]);
        }
#pragma unroll
        for (int df = 0; df < 4; ++df) {
            short8 vf1 = *(short8*)(Vt + (df * 16 + lr) * 64 + (((4 + lg) ^ swz) << 3));
            oacc[df] = MFMA16(pf1, vf1, oacc[df]);
        }
    }

    const int b = bh / 12, h = bh % 12;
    float rinv[4];
#pragma unroll
    for (int r = 0; r < 4; ++r) {
        float lr_ = __shfl(lrun, lg * 4 + r);
        rinv[r] = __builtin_amdgcn_rcpf(lr_);
    }
#pragma unroll
    for (int df = 0; df < 4; ++df)
#pragma unroll
        for (int r = 0; r < 4; ++r) {
            int q = q0 + wid * 16 + lg * 4 + r;
            int d = df * 16 + lr;
            float o = oacc[df][r] * rinv[r];
            ctx[((size_t)b * 1024 + q) * 768 + h * 64 + d] = f2bf(o);
        }
}

// ---- fused: x2 = x + LN1(ctx);  ln2b = bf16(LN2(x2)) ----
__global__ __launch_bounds__(256) void ln_fused(const float* __restrict__ x,
                                                const short* __restrict__ ctx,
                                                const float* __restrict__ g1,
                                                const float* __restrict__ b1,
                                                const float* __restrict__ g2,
                                                const float* __restrict__ b2,
                                                float* __restrict__ x2,
                                                short* __restrict__ ln2b) {
    const int row = blockIdx.x, t = threadIdx.x;
    const int wid = t >> 6, lane = t & 63;
    __shared__ float red[8];

    float c[3], xv[3];
#pragma unroll
    for (int j = 0; j < 3; ++j) {
        int idx = t + 256 * j;
        c[j] = bf2f(ctx[(size_t)row * 768 + idx]);
        xv[j] = x[(size_t)row * 768 + idx];
    }
    float s = c[0] + c[1] + c[2];
    float s2 = c[0] * c[0] + c[1] * c[1] + c[2] * c[2];
#pragma unroll
    for (int off = 32; off > 0; off >>= 1) { s += __shfl_down(s, off); s2 += __shfl_down(s2, off); }
    if (lane == 0) { red[wid] = s; red[4 + wid] = s2; }
    __syncthreads();
    s = red[0] + red[1] + red[2] + red[3];
    s2 = red[4] + red[5] + red[6] + red[7];
    float mu = s * (1.0f / 768.0f);
    float rstd = rsqrtf(s2 * (1.0f / 768.0f) - mu * mu + 1e-5f);

    float y[3];
#pragma unroll
    for (int j = 0; j < 3; ++j) {
        int idx = t + 256 * j;
        y[j] = xv[j] + (c[j] - mu) * rstd * g1[idx] + b1[idx];
        x2[(size_t)row * 768 + idx] = y[j];
    }
    __syncthreads();
    s = y[0] + y[1] + y[2];
    s2 = y[0] * y[0] + y[1] * y[1] + y[2] * y[2];
#pragma unroll
    for (int off = 32; off > 0; off >>= 1) { s += __shfl_down(s, off); s2 += __shfl_down(s2, off); }
    if (lane == 0) { red[wid] = s; red[4 + wid] = s2; }
    __syncthreads();
    s = red[0] + red[1] + red[2] + red[3];
    s2 = red[4] + red[5] + red[6] + red[7];
    float mu2 = s * (1.0f / 768.0f);
    float rstd2 = rsqrtf(s2 * (1.0f / 768.0f) - mu2 * mu2 + 1e-5f);
#pragma unroll
    for (int j = 0; j < 3; ++j) {
        int idx = t + 256 * j;
        ln2b[(size_t)row * 768 + idx] = f2bf((y[j] - mu2) * rstd2 * g2[idx] + b2[idx]);
    }
}

extern "C" void kernel_launch(void* const* d_in, const int* in_sizes, int n_in,
                              void* d_out, int out_size, void* d_ws, size_t ws_size,
                              hipStream_t stream) {
    const float* x    = (const float*)d_in[0];
    const float* wq   = (const float*)d_in[1];
    const float* bq   = (const float*)d_in[2];
    const float* wk   = (const float*)d_in[3];
    const float* bk   = (const float*)d_in[4];
    const float* wv   = (const float*)d_in[5];
    const float* bv   = (const float*)d_in[6];
    const float* g1   = (const float*)d_in[7];
    const float* b1   = (const float*)d_in[8];
    const float* g2   = (const float*)d_in[9];
    const float* b2   = (const float*)d_in[10];
    const float* w_in = (const float*)d_in[11];
    const float* b_in = (const float*)d_in[12];
    const float* w_out  = (const float*)d_in[13];
    const float* b_out  = (const float*)d_in[14];
    float* out = (float*)d_out;

    char* ws = (char*)d_ws;
    short* xb     = (short*)(ws + 0);          // 12.6 MB; dead after QKV gemm
    short* vT     = (short*)(ws + 0);          // aliases xb
    short* qb     = (short*)(ws + 12582912);   // [96][1024][64] q,k,v contiguous
    short* kb     = (short*)(ws + 25165824);
    short* vb     = (short*)(ws + 37748736);
    short* h1     = (short*)(ws + 0);          // 50.3 MB, aliases xb/vT..vb
    short* ctx    = (short*)(ws + 50331648);   // 12.6 MB
    float* x2     = (float*)(ws + 62914560);   // 25.2 MB
    float* bqkv   = (float*)(ws + 62914560);   // aliases x2 start
    short* ln2b   = (short*)(ws + 88080384);   // 12.6 MB
    short* wqkvT  = (short*)(ws + 100663296);  // [2304][768]
    short* w_inT  = (short*)(ws + 104202240);  // [3072][768]
    short* w_outT = (short*)(ws + 108920832);  // [768][3072]

    // stage 0
    cast_kernel<<<6144, 256, 0, stream>>>(x, xb, 1572864);
    concat_bias<<<9, 256, 0, stream>>>(bq, bk, bv, bqkv);
    transpose_cast<<<dim3(24, 24), 256, 0, stream>>>(wq, wqkvT, 768, 768);
    transpose_cast<<<dim3(24, 24), 256, 0, stream>>>(wk, wqkvT + 768 * 768, 768, 768);
    transpose_cast<<<dim3(24, 24), 256, 0, stream>>>(wv, wqkvT + 2 * 768 * 768, 768, 768);
    transpose_cast<<<dim3(96, 24), 256, 0, stream>>>(w_in, w_inT, 768, 3072);
    transpose_cast<<<dim3(24, 96), 256, 0, stream>>>(w_out, w_outT, 3072, 768);

    // stage 1: fused QKV projection (q pre-scaled in epilogue)
    // grid 1152 = 8 XCDs x (8 row-blocks x 18 col-blocks)
    gemm_kernel<0, 4, 128, 18><<<1152, 256, 0, stream>>>(xb, wqkvT, bqkv, qb, nullptr, 8192, 2304, 768);

    // stage 1.5: V transpose
    transpose_v<<<dim3(2, 32, 96), 256, 0, stream>>>(vb, vT);

    // stage 2: attention
    attn_kernel<<<dim3(96, 16), 256, 0, stream>>>(qb, kb, vT, ctx);

    // stage 3
    ln_fused<<<8192, 256, 0, stream>>>(x, ctx, g1, b1, g2, b2, x2, ln2b);

    // stage 4: MLP
    // MLP1: grid 1536 = 8 x (8 x 24)
    gemm_kernel<1, 4, 128, 24><<<1536, 256, 0, stream>>>(ln2b, w_inT, b_in, h1, nullptr, 8192, 3072, 768);
    // MLP2: MB=64 tile -> grid 768 = 8 x (16 x 6) = exactly 3 blocks/CU
    gemm_kernel<2, 4, 64, 6><<<768, 256, 0, stream>>>(h1, w_outT, b_out, out, x2, 8192, 768, 3072);
}

// Round 10
// 348.542 us; speedup vs baseline: 1.1392x; 1.0681x over previous
//
#include <hip/hip_runtime.h>
#include <math.h>

// ---- types ----
typedef __attribute__((ext_vector_type(8))) short short8;   // 8 bf16
typedef __attribute__((ext_vector_type(4))) float f32x4;

#define MFMA16(a, b, c) __builtin_amdgcn_mfma_f32_16x16x32_bf16(a, b, c, 0, 0, 0)

__device__ __forceinline__ unsigned cvtpk(float a, float b) {
    unsigned r; asm("v_cvt_pk_bf16_f32 %0, %1, %2" : "=v"(r) : "v"(a), "v"(b)); return r;
}
__device__ __forceinline__ short f2bf(float f) { return (short)cvtpk(f, f); }
__device__ __forceinline__ float bf2f(short s) {
    union { unsigned u; float f; } v; v.u = ((unsigned)(unsigned short)s) << 16;
    return v.f;
}
// tanh-form GELU: max abs err vs erf-GELU ~3e-3, well under the 0.18 threshold.
__device__ __forceinline__ float gelu(float v) {
    float u = v * (1.0f + 0.044715f * v * v);
    float e = exp2f(-2.3021184f * u);
    return v * __builtin_amdgcn_rcpf(1.0f + e);
}
__device__ __forceinline__ float max3f(float a, float b, float c) {
    float d; asm("v_max3_f32 %0, %1, %2, %3" : "=v"(d) : "v"(a), "v"(b), "v"(c)); return d;
}
// async global->LDS, 16B per lane; lds dest = wave-uniform base + lane*16 (m97/m104)
__device__ __forceinline__ void async16(const short* g, short* l) {
    __builtin_amdgcn_global_load_lds((const __attribute__((address_space(1))) void*)g,
                                     (__attribute__((address_space(3))) void*)l, 16, 0, 0);
}

// Redistribute 8 per-lane P values into the MFMA A-frag layout (see round-5 note).
__device__ __forceinline__ short8 build_pfrag(int lg, float x0, float x1, float x2, float x3,
                                              float x4, float x5, float x6, float x7) {
    unsigned a0 = cvtpk(x0, x1), a1 = cvtpk(x2, x3);
    unsigned b0 = cvtpk(x4, x5), b1 = cvtpk(x6, x7);
    unsigned u0 = (lg < 2) ? b0 : a0, u1 = (lg < 2) ? b1 : a1;
    unsigned v0 = (unsigned)__shfl_xor((int)u0, 32), v1 = (unsigned)__shfl_xor((int)u1, 32);
    unsigned w0 = (lg < 2) ? a0 : b0, w1 = (lg < 2) ? a1 : b1;
    bool sw = ((lg ^ (lg >> 1)) & 1) != 0;
    unsigned s0 = sw ? w0 : v0, s1 = sw ? w1 : v1;
    unsigned r0 = (unsigned)__shfl_xor((int)s0, 16), r1 = (unsigned)__shfl_xor((int)s1, 16);
    union { unsigned u[4]; short8 s; } o;
    o.u[0] = (lg & 1) ? r0 : ((lg == 0) ? w0 : v0);
    o.u[1] = (lg & 1) ? r1 : ((lg == 0) ? w1 : v1);
    o.u[2] = (lg & 1) ? ((lg == 1) ? v0 : w0) : r0;
    o.u[3] = (lg & 1) ? ((lg == 1) ? v1 : w1) : r1;
    return o.s;
}

// ---- fused prep: cast x, concat biases, transpose+cast all 5 weight matrices ----
// block ranges: [0,6144) cast | [6144,6153) bias | [6153,7881) wq/wk/wv |
//               [7881,10185) w_in | [10185,12489) w_out
__global__ __launch_bounds__(256) void prep_kernel(
    const float* __restrict__ x, short* __restrict__ xb,
    const float* __restrict__ bq, const float* __restrict__ bk,
    const float* __restrict__ bv, float* __restrict__ bqkv,
    const float* __restrict__ wq, const float* __restrict__ wk,
    const float* __restrict__ wv, short* __restrict__ wqkvT,
    const float* __restrict__ w_in, short* __restrict__ w_inT,
    const float* __restrict__ w_out, short* __restrict__ w_outT) {
    __shared__ float tile[32][33];
    const int w = blockIdx.x, t = threadIdx.x;
    if (w < 6144) {  // cast x -> bf16, 4 floats/thread
        int i = w * 256 + t;
        float4 v = ((const float4*)x)[i];
        uint2 o; o.x = cvtpk(v.x, v.y); o.y = cvtpk(v.z, v.w);
        ((uint2*)xb)[i] = o;
        return;
    }
    if (w < 6153) {  // bias concat
        int i = (w - 6144) * 256 + t;
        if (i < 768) bqkv[i] = bq[i];
        else if (i < 1536) bqkv[i] = bk[i - 768];
        else if (i < 2304) bqkv[i] = bv[i - 1536];
        return;
    }
    const float* in; short* out; int K, N, n0, k0;
    if (w < 7881) {
        int v_ = w - 6153, z = v_ / 576, u = v_ - z * 576;
        in = (z == 0) ? wq : (z == 1) ? wk : wv;
        out = wqkvT + (size_t)z * 768 * 768;
        K = 768; N = 768; n0 = (u % 24) * 32; k0 = (u / 24) * 32;
    } else if (w < 10185) {
        int u = w - 7881;
        in = w_in; out = w_inT; K = 768; N = 3072;
        n0 = (u % 96) * 32; k0 = (u / 96) * 32;
    } else {
        int u = w - 10185;
        in = w_out; out = w_outT; K = 3072; N = 768;
        n0 = (u % 24) * 32; k0 = (u / 24) * 32;
    }
    int tx = t & 31, ty = t >> 5;  // 32 x 8
#pragma unroll
    for (int r = 0; r < 4; ++r)
        tile[ty + r * 8][tx] = in[(size_t)(k0 + ty + r * 8) * N + n0 + tx];
    __syncthreads();
#pragma unroll
    for (int r = 0; r < 4; ++r) {
        int rr = ty + r * 8;
        out[(size_t)(n0 + rr) * K + k0 + tx] = f2bf(tile[tx][rr]);
    }
}

// ---- per-head V transpose: in [96][1024 s][64 d] bf16 -> out [96][64 d][1024 s] ----
__global__ __launch_bounds__(256) void transpose_v(const short* __restrict__ in,
                                                   short* __restrict__ out) {
    __shared__ short tile[32][33];
    const int bh = blockIdx.z;
    const int s0 = blockIdx.y * 32, d0 = blockIdx.x * 32;
    const short* src = in + (size_t)bh * 1024 * 64;
    short* dst = out + (size_t)bh * 64 * 1024;
    int tx = threadIdx.x & 31, ty = threadIdx.x >> 5;  // 32 x 8
#pragma unroll
    for (int r = 0; r < 4; ++r)
        tile[ty + r * 8][tx] = src[(size_t)(s0 + ty + r * 8) * 64 + d0 + tx];
    __syncthreads();
#pragma unroll
    for (int r = 0; r < 4; ++r) {
        int rr = ty + r * 8;
        dst[(size_t)(d0 + rr) * 1024 + s0 + tx] = tile[tx][rr];
    }
}

// ---- generic bf16 GEMM: C[M,N] = A[M,K] @ B[K,N] (+bias, epilogue) ----
// BK=64, XOR-swizzled LDS (both-sides), MB x NF*32 tile, 4 waves (2x2),
// 1-D grid with bijective XCD swizzle. Epilogues use packed bf16 converts.
template <int EPI, int NF, int MB, int NXB>
__global__ __launch_bounds__(256) void gemm_kernel(const short* __restrict__ A,
                                                   const short* __restrict__ Bt,
                                                   const float* __restrict__ bias,
                                                   void* __restrict__ Cout,
                                                   const float* __restrict__ resid,
                                                   int M, int N, int K) {
    const int TN = NF * 32;
    const int FM = MB / 32;
    const int t = threadIdx.x;
    const int wid = t >> 6, lane = t & 63;
    const int wm = wid >> 1, wn = wid & 1;
    const int lr = lane & 15, lg = lane >> 4;

    const int wgid = blockIdx.x;
    const int xcd = wgid & 7;
    const int loc = wgid >> 3;
    const int rpx = (M / MB) >> 3;
    const int rb = xcd * rpx + loc / NXB;
    const int cb = loc % NXB;
    const int row0 = rb * MB, col0 = cb * TN;

    __shared__ __align__(16) short As[MB * 64];
    __shared__ __align__(16) short Bs[NF * 32 * 64];

    f32x4 acc[FM][NF];
#pragma unroll
    for (int i = 0; i < FM; ++i)
#pragma unroll
        for (int j = 0; j < NF; ++j) acc[i][j] = (f32x4){0.f, 0.f, 0.f, 0.f};

    const int aRow = wid * 8 + (lane >> 3);
    const int aK = ((lane & 7) ^ (lane >> 3)) << 3;
    const short* Ag = A + (size_t)(row0 + aRow) * K + aK;
    const short* Bg = Bt + (size_t)(col0 + aRow) * K + aK;
    short* AsW = As + wid * 8 * 64;
    short* BsW = Bs + wid * 8 * 64;
    const int swz = lr & 7;

    for (int k0 = 0; k0 < K; k0 += 64) {
        __syncthreads();
#pragma unroll
        for (int j = 0; j < MB / 32; ++j)
            async16(Ag + (size_t)(j * 32) * K + k0, AsW + j * 32 * 64);
#pragma unroll
        for (int j = 0; j < NF; ++j)
            async16(Bg + (size_t)(j * 32) * K + k0, BsW + j * 32 * 64);
        __syncthreads();

#pragma unroll
        for (int ks = 0; ks < 2; ++ks) {
            const int rdofs = ((ks * 4 + lg) ^ swz) << 3;
            short8 af[FM], bfr[NF];
#pragma unroll
            for (int i = 0; i < FM; ++i)
                af[i] = *(short8*)(As + (wm * (MB / 2) + i * 16 + lr) * 64 + rdofs);
#pragma unroll
            for (int i = 0; i < NF; ++i)
                bfr[i] = *(short8*)(Bs + (wn * (NF * 16) + i * 16 + lr) * 64 + rdofs);
#pragma unroll
            for (int mi = 0; mi < FM; ++mi)
#pragma unroll
                for (int ni = 0; ni < NF; ++ni)
                    acc[mi][ni] = MFMA16(af[mi], bfr[ni], acc[mi][ni]);
        }
    }

#pragma unroll
    for (int mi = 0; mi < FM; ++mi)
#pragma unroll
        for (int ni = 0; ni < NF; ++ni)
#pragma unroll
            for (int rp = 0; rp < 4; rp += 2) {
                int row = row0 + wm * (MB / 2) + mi * 16 + lg * 4 + rp;
                int col = col0 + wn * (NF * 16) + ni * 16 + lr;
                float v0 = acc[mi][ni][rp] + bias[col];
                float v1 = acc[mi][ni][rp + 1] + bias[col];
                if constexpr (EPI == 0) {
                    unsigned uc = (unsigned)col;
                    unsigned m = uc / 768u;
                    unsigned rest = uc - m * 768u;
                    unsigned h = rest >> 6, d = rest & 63u;
                    int b = row >> 10, s_ = row & 1023;
                    if (m == 0u) { v0 *= 0.18033688011f; v1 *= 0.18033688011f; }
                    unsigned pk = cvtpk(v0, v1);
                    size_t idx = ((((size_t)m * 96 + (size_t)b * 12 + h) * 1024 + s_) * 64) + d;
                    ((short*)Cout)[idx] = (short)pk;
                    ((short*)Cout)[idx + 64] = (short)(pk >> 16);  // s_+1, same b (r<3)
                } else if constexpr (EPI == 1) {
                    unsigned pk = cvtpk(gelu(v0), gelu(v1));
                    size_t idx = (size_t)row * N + col;
                    ((short*)Cout)[idx] = (short)pk;
                    ((short*)Cout)[idx + N] = (short)(pk >> 16);
                } else {
                    size_t idx = (size_t)row * N + col;
                    ((float*)Cout)[idx] = resid[idx] + gelu(v0);
                    ((float*)Cout)[idx + N] = resid[idx + N] + gelu(v1);
                }
            }
}

// ---- flash attention: QBLK=128 (2 q-groups/wave), swapped QK^T, in-register
//      softmax, defer-max, async16+XOR-swizzled K/V staging; Q direct from global.
__global__ __launch_bounds__(256) void attn_kernel(const short* __restrict__ Q,
                                                   const short* __restrict__ Kg,
                                                   const short* __restrict__ VTg,
                                                   short* __restrict__ ctx) {
    const int bh = blockIdx.x;        // 0..95
    const int q0 = blockIdx.y * 128;  // 8 q-blocks
    const int t = threadIdx.x, wid = t >> 6, lane = t & 63;
    const int lr = lane & 15, lg = lane >> 4;

    __shared__ __align__(16) short Ks[64 * 64];
    __shared__ __align__(16) short Vt[64 * 64];  // [d][k]

    const size_t base = (size_t)bh * 1024 * 64;
    const size_t vbase = (size_t)bh * 64 * 1024;

    const int srow = lane >> 3;
    const int lslot8 = ((lane & 7) ^ srow) << 3;
    const int r0w = wid * 16;
    const int swz = lr & 7;

    // Q fragments straight from global (L2-resident, read once)
    short8 qf[2][2];
    {
        const short* qrow = Q + base + (size_t)(q0 + wid * 32 + lr) * 64;
        qf[0][0] = *(const short8*)(qrow + lg * 8);
        qf[0][1] = *(const short8*)(qrow + 32 + lg * 8);
        qf[1][0] = *(const short8*)(qrow + 16 * 64 + lg * 8);
        qf[1][1] = *(const short8*)(qrow + 16 * 64 + 32 + lg * 8);
    }

    f32x4 oacc[2][4];
#pragma unroll
    for (int g = 0; g < 2; ++g)
#pragma unroll
        for (int i = 0; i < 4; ++i) oacc[g][i] = (f32x4){0.f, 0.f, 0.f, 0.f};
    float mrun[2] = {-1e30f, -1e30f}, lrun[2] = {0.f, 0.f};

    const short* kg = Kg + base + (size_t)(r0w + srow) * 64 + lslot8;
    const short* vg = VTg + vbase + (size_t)(r0w + srow) * 1024 + lslot8;

    for (int kt = 0; kt < 16; ++kt) {
        const int krow0 = kt * 64;
        __syncthreads();
        async16(kg + (size_t)krow0 * 64, Ks + r0w * 64);
        async16(kg + (size_t)(krow0 + 8) * 64, Ks + (r0w + 8) * 64);
        async16(vg + krow0, Vt + r0w * 64);
        async16(vg + krow0 + 8 * 1024, Vt + (r0w + 8) * 64);
        __syncthreads();

        // S^T = mfma(K, Q): K-frags shared across both q-groups
        f32x4 sfr[2][4];
#pragma unroll
        for (int cf = 0; cf < 4; ++cf) {
            short8 kf0 = *(short8*)(Ks + (cf * 16 + lr) * 64 + ((lg ^ swz) << 3));
            short8 kf1 = *(short8*)(Ks + (cf * 16 + lr) * 64 + (((4 + lg) ^ swz) << 3));
#pragma unroll
            for (int g = 0; g < 2; ++g) {
                f32x4 s = (f32x4){0.f, 0.f, 0.f, 0.f};
                s = MFMA16(kf0, qf[g][0], s);
                s = MFMA16(kf1, qf[g][1], s);
                sfr[g][cf] = s;
            }
        }

        short8 pf[2][2];
#pragma unroll
        for (int g = 0; g < 2; ++g) {
            float g0 = max3f(sfr[g][0][0], sfr[g][0][1], sfr[g][0][2]);
            float g1 = max3f(sfr[g][0][3], sfr[g][1][0], sfr[g][1][1]);
            float g2 = max3f(sfr[g][1][2], sfr[g][1][3], sfr[g][2][0]);
            float g3 = max3f(sfr[g][2][1], sfr[g][2][2], sfr[g][2][3]);
            float g4 = max3f(sfr[g][3][0], sfr[g][3][1], sfr[g][3][2]);
            float mx = fmaxf(max3f(g0, g1, g2), max3f(g3, g4, sfr[g][3][3]));
            mx = fmaxf(mx, __shfl_xor(mx, 16));
            mx = fmaxf(mx, __shfl_xor(mx, 32));

            if (!__all(mx <= mrun[g] + 8.0f)) {
                float mnew = fmaxf(mrun[g], mx);
                float fac = exp2f(mrun[g] - mnew);
                lrun[g] *= fac;
#pragma unroll
                for (int r = 0; r < 4; ++r) {
                    float fr = __shfl(fac, lg * 4 + r);
#pragma unroll
                    for (int df = 0; df < 4; ++df) oacc[g][df][r] *= fr;
                }
                mrun[g] = mnew;
            }

            float p[16];
#pragma unroll
            for (int cf = 0; cf < 4; ++cf)
#pragma unroll
                for (int r = 0; r < 4; ++r) p[cf * 4 + r] = exp2f(sfr[g][cf][r] - mrun[g]);
            float s0 = (p[0] + p[1]) + (p[2] + p[3]);
            float s1 = (p[4] + p[5]) + (p[6] + p[7]);
            float s2 = (p[8] + p[9]) + (p[10] + p[11]);
            float s3 = (p[12] + p[13]) + (p[14] + p[15]);
            float rs = (s0 + s1) + (s2 + s3);
            rs += __shfl_xor(rs, 16);
            rs += __shfl_xor(rs, 32);
            lrun[g] += rs;

            pf[g][0] = build_pfrag(lg, p[0], p[1], p[2], p[3], p[4], p[5], p[6], p[7]);
            pf[g][1] = build_pfrag(lg, p[8], p[9], p[10], p[11], p[12], p[13], p[14], p[15]);
        }

        // PV: V-frags shared across both q-groups
#pragma unroll
        for (int df = 0; df < 4; ++df) {
            short8 vf0 = *(short8*)(Vt + (df * 16 + lr) * 64 + ((lg ^ swz) << 3));
            oacc[0][df] = MFMA16(pf[0][0], vf0, oacc[0][df]);
            oacc[1][df] = MFMA16(pf[1][0], vf0, oacc[1][df]);
        }
#pragma unroll
        for (int df = 0; df < 4; ++df) {
            short8 vf1 = *(short8*)(Vt + (df * 16 + lr) * 64 + (((4 + lg) ^ swz) << 3));
            oacc[0][df] = MFMA16(pf[0][1], vf1, oacc[0][df]);
            oacc[1][df] = MFMA16(pf[1][1], vf1, oacc[1][df]);
        }
    }

    const int b = bh / 12, h = bh % 12;
#pragma unroll
    for (int g = 0; g < 2; ++g) {
        float rinv[4];
#pragma unroll
        for (int r = 0; r < 4; ++r) {
            float lr_ = __shfl(lrun[g], lg * 4 + r);
            rinv[r] = __builtin_amdgcn_rcpf(lr_);
        }
#pragma unroll
        for (int df = 0; df < 4; ++df)
#pragma unroll
            for (int rp = 0; rp < 4; rp += 2) {
                int q = q0 + wid * 32 + g * 16 + lg * 4 + rp;
                int d = df * 16 + lr;
                unsigned pk = cvtpk(oacc[g][df][rp] * rinv[rp],
                                    oacc[g][df][rp + 1] * rinv[rp + 1]);
                size_t idx = ((size_t)b * 1024 + q) * 768 + h * 64 + d;
                ctx[idx] = (short)pk;
                ctx[idx + 768] = (short)(pk >> 16);
            }
    }
}

// ---- fused: x2 = x + LN1(ctx);  ln2b = bf16(LN2(x2)) ----
__global__ __launch_bounds__(256) void ln_fused(const float* __restrict__ x,
                                                const short* __restrict__ ctx,
                                                const float* __restrict__ g1,
                                                const float* __restrict__ b1,
                                                const float* __restrict__ g2,
                                                const float* __restrict__ b2,
                                                float* __restrict__ x2,
                                                short* __restrict__ ln2b) {
    const int row = blockIdx.x, t = threadIdx.x;
    const int wid = t >> 6, lane = t & 63;
    __shared__ float red[8];

    float c[3], xv[3];
#pragma unroll
    for (int j = 0; j < 3; ++j) {
        int idx = t + 256 * j;
        c[j] = bf2f(ctx[(size_t)row * 768 + idx]);
        xv[j] = x[(size_t)row * 768 + idx];
    }
    float s = c[0] + c[1] + c[2];
    float s2 = c[0] * c[0] + c[1] * c[1] + c[2] * c[2];
#pragma unroll
    for (int off = 32; off > 0; off >>= 1) { s += __shfl_down(s, off); s2 += __shfl_down(s2, off); }
    if (lane == 0) { red[wid] = s; red[4 + wid] = s2; }
    __syncthreads();
    s = red[0] + red[1] + red[2] + red[3];
    s2 = red[4] + red[5] + red[6] + red[7];
    float mu = s * (1.0f / 768.0f);
    float rstd = rsqrtf(s2 * (1.0f / 768.0f) - mu * mu + 1e-5f);

    float y[3];
#pragma unroll
    for (int j = 0; j < 3; ++j) {
        int idx = t + 256 * j;
        y[j] = xv[j] + (c[j] - mu) * rstd * g1[idx] + b1[idx];
        x2[(size_t)row * 768 + idx] = y[j];
    }
    __syncthreads();
    s = y[0] + y[1] + y[2];
    s2 = y[0] * y[0] + y[1] * y[1] + y[2] * y[2];
#pragma unroll
    for (int off = 32; off > 0; off >>= 1) { s += __shfl_down(s, off); s2 += __shfl_down(s2, off); }
    if (lane == 0) { red[wid] = s; red[4 + wid] = s2; }
    __syncthreads();
    s = red[0] + red[1] + red[2] + red[3];
    s2 = red[4] + red[5] + red[6] + red[7];
    float mu2 = s * (1.0f / 768.0f);
    float rstd2 = rsqrtf(s2 * (1.0f / 768.0f) - mu2 * mu2 + 1e-5f);
#pragma unroll
    for (int j = 0; j < 3; ++j) {
        int idx = t + 256 * j;
        ln2b[(size_t)row * 768 + idx] = f2bf((y[j] - mu2) * rstd2 * g2[idx] + b2[idx]);
    }
}

extern "C" void kernel_launch(void* const* d_in, const int* in_sizes, int n_in,
                              void* d_out, int out_size, void* d_ws, size_t ws_size,
                              hipStream_t stream) {
    const float* x    = (const float*)d_in[0];
    const float* wq   = (const float*)d_in[1];
    const float* bq   = (const float*)d_in[2];
    const float* wk   = (const float*)d_in[3];
    const float* bk   = (const float*)d_in[4];
    const float* wv   = (const float*)d_in[5];
    const float* bv   = (const float*)d_in[6];
    const float* g1   = (const float*)d_in[7];
    const float* b1   = (const float*)d_in[8];
    const float* g2   = (const float*)d_in[9];
    const float* b2   = (const float*)d_in[10];
    const float* w_in = (const float*)d_in[11];
    const float* b_in = (const float*)d_in[12];
    const float* w_out  = (const float*)d_in[13];
    const float* b_out  = (const float*)d_in[14];
    float* out = (float*)d_out;

    char* ws = (char*)d_ws;
    short* xb     = (short*)(ws + 0);          // 12.6 MB; dead after QKV gemm
    short* vT     = (short*)(ws + 0);          // aliases xb
    short* qb     = (short*)(ws + 12582912);   // [96][1024][64] q,k,v contiguous
    short* kb     = (short*)(ws + 25165824);
    short* vb     = (short*)(ws + 37748736);
    short* h1     = (short*)(ws + 0);          // 50.3 MB, aliases xb/vT..vb
    short* ctx    = (short*)(ws + 50331648);   // 12.6 MB
    float* x2     = (float*)(ws + 62914560);   // 25.2 MB
    float* bqkv   = (float*)(ws + 62914560);   // aliases x2 start
    short* ln2b   = (short*)(ws + 88080384);   // 12.6 MB
    short* wqkvT  = (short*)(ws + 100663296);  // [2304][768]
    short* w_inT  = (short*)(ws + 104202240);  // [3072][768]
    short* w_outT = (short*)(ws + 108920832);  // [768][3072]

    // stage 0: single fused prep launch (cast + bias concat + 5 transposes)
    prep_kernel<<<12489, 256, 0, stream>>>(x, xb, bq, bk, bv, bqkv,
                                           wq, wk, wv, wqkvT, w_in, w_inT, w_out, w_outT);

    // stage 1: fused QKV projection (q pre-scaled in epilogue)
    gemm_kernel<0, 4, 128, 18><<<1152, 256, 0, stream>>>(xb, wqkvT, bqkv, qb, nullptr, 8192, 2304, 768);

    // stage 1.5: V transpose
    transpose_v<<<dim3(2, 32, 96), 256, 0, stream>>>(vb, vT);

    // stage 2: attention (QBLK=128)
    attn_kernel<<<dim3(96, 8), 256, 0, stream>>>(qb, kb, vT, ctx);

    // stage 3
    ln_fused<<<8192, 256, 0, stream>>>(x, ctx, g1, b1, g2, b2, x2, ln2b);

    // stage 4: MLP
    gemm_kernel<1, 4, 128, 24><<<1536, 256, 0, stream>>>(ln2b, w_inT, b_in, h1, nullptr, 8192, 3072, 768);
    gemm_kernel<2, 4, 64, 6><<<768, 256, 0, stream>>>(h1, w_outT, b_out, out, x2, 8192, 768, 3072);
}